// Round 2
// baseline (1861.157 us; speedup 1.0000x reference)
//
#include <hip/hip_runtime.h>

// HiPPO-LegT forward scan, fp32.
//   c_t = c_{t-1} @ A^T + f_t * B    (512 sequences, N=256, L=1024)
//
// R2. Model from R0/R1 counters: VALUBusy (gfx94x fallback formula) is 2x
// inflated (SIMD-16 assumption); real VALU issue ~20%. Step time matches DS
// instruction count x ~6 cyc: the kernel is DS-PIPE ISSUE BOUND (512
// ds_read_b128 + writes per CU-step). Fix: remap threads from (row, 64-col
// block) to (4-row tile, 16-col chunk):
//   - each c value loaded is reused over 4 rows in registers -> DS reads
//     drop 4x (32 -> 8 b128/thread/step); c-write becomes 1 masked b128/wave.
//   - reduction widens 4 -> 16 lanes, kept on the VALU pipe via DPP
//     quad_perm(xor1,xor2) + row_ror:4 + row_ror:8 (rotation all-reduce).
//   - LDS chunks padded to 20 floats: 16 distinct read addrs/instr cover all
//     32 banks 2-way (free), 4-lane same-address broadcast on top.
// Prediction: dur 1490 -> ~450-650us; VALUBusy -> 85-100% (new co-limiter);
// bank conflicts ~0. Falsifier: dur >= 900us & VALUBusy < 60% => broadcast
// dedup assumption wrong -> next: R=8/K=8.

#define LSTEPS 1024
#define NCH 20   // LDS chunk stride in floats: 16 payload + 4 pad

typedef float v2f __attribute__((ext_vector_type(2)));

#define DPP_ADD(v, ctrl) \
  ((v) + __int_as_float(__builtin_amdgcn_update_dpp( \
       0, __float_as_int(v), (ctrl), 0xF, 0xF, false)))

__device__ __forceinline__ float red16(float v) {
  // all-reduce over the 16 lanes of a DPP row (lanes ck=0..15 of a rowtile)
  v = DPP_ADD(v, 0xB1);   // quad_perm [1,0,3,2]  : + lane^1
  v = DPP_ADD(v, 0x4E);   // quad_perm [2,3,0,1]  : + lane^2  -> quad sums
  v = DPP_ADD(v, 0x124);  // row_ror:4            : + next quad
  v = DPP_ADD(v, 0x128);  // row_ror:8            : + other half
  return v;
}

__global__ __launch_bounds__(1024, 4) void hippo_legt_kernel(
    const float* __restrict__ inp,   // (512, 1024) = (B*M, L)
    const float* __restrict__ A,     // (256, 256) row-major (discrete Ad)
    const float* __restrict__ Bvec,  // (256)      (discrete Bd)
    float* __restrict__ out)         // (1024, 512, 256)
{
    __shared__ __attribute__((aligned(16))) float cbuf[2][2][16][NCH]; // [buf][seq][chunk][pad]
    __shared__ __attribute__((aligned(16))) float fbuf[2][LSTEPS];

    const int tid  = threadIdx.x;
    const int rt   = tid >> 4;   // rowtile 0..63 : rows 4rt..4rt+3
    const int ck   = tid & 15;   // col-chunk 0..15: cols 16ck..16ck+15
    const int sq   = ck & 1;     // writer lanes: ck==0 -> seq0, ck==1 -> seq1
    const int seq0 = blockIdx.x * 2;

    // A fragment: A[4rt+i][16ck + 0..15] as v2f pairs -> 64 VGPRs.
    v2f a[4][8];
    #pragma unroll
    for (int i = 0; i < 4; ++i) {
        const float4* Ar =
            reinterpret_cast<const float4*>(A + (size_t)(4 * rt + i) * 256 + 16 * ck);
        #pragma unroll
        for (int q = 0; q < 4; ++q) {
            const float4 t = Ar[q];
            a[i][2 * q]     = v2f{t.x, t.y};
            a[i][2 * q + 1] = v2f{t.z, t.w};
        }
    }
    const float4 bd4 = reinterpret_cast<const float4*>(Bvec)[rt];

    // Preload f for both sequences: 2048 floats = 512 float4, coalesced.
    if (tid < 512) {
        reinterpret_cast<float4*>(&fbuf[0][0])[tid] =
            reinterpret_cast<const float4*>(inp + (size_t)seq0 * LSTEPS)[tid];
    }
    // Zero initial state buffer (buf 0, both seqs): 2*16*20 = 640 floats.
    if (tid < 2 * 16 * NCH) (&cbuf[0][0][0][0])[tid] = 0.0f;
    __syncthreads();

    // Per-lane invariant addresses (no per-step address math).
    const float4* r00 = reinterpret_cast<const float4*>(&cbuf[0][0][ck][0]);
    const float4* r01 = reinterpret_cast<const float4*>(&cbuf[0][1][ck][0]);
    const float4* r10 = reinterpret_cast<const float4*>(&cbuf[1][0][ck][0]);
    const float4* r11 = reinterpret_cast<const float4*>(&cbuf[1][1][ck][0]);
    float4* w0 = reinterpret_cast<float4*>(&cbuf[0][sq][rt >> 2][(rt & 3) * 4]);
    float4* w1 = reinterpret_cast<float4*>(&cbuf[1][sq][rt >> 2][(rt & 3) * 4]);
    float4* op = reinterpret_cast<float4*>(out + (size_t)(seq0 + sq) * 256 + rt * 4);
    const bool writer = (ck < 2);
    const size_t ostride = (size_t)512 * 256 / 4;   // float4s per time step

    auto step = [&](const float4* __restrict__ r0, const float4* __restrict__ r1,
                    float4* w, float4* o, int t) {
        v2f acc0[4], acc1[4];
        // q = 0: initialize accumulators with pk_mul (no zero-init movs)
        {
            const float4 u = r0[0];
            const float4 v = r1[0];
            const v2f ulo{u.x, u.y}, uhi{u.z, u.w};
            const v2f vlo{v.x, v.y}, vhi{v.z, v.w};
            #pragma unroll
            for (int i = 0; i < 4; ++i) {
                acc0[i] = a[i][0] * ulo;  acc0[i] += a[i][1] * uhi;
                acc1[i] = a[i][0] * vlo;  acc1[i] += a[i][1] * vhi;
            }
        }
        #pragma unroll
        for (int q = 1; q < 4; ++q) {
            const float4 u = r0[q];
            const float4 v = r1[q];
            const v2f ulo{u.x, u.y}, uhi{u.z, u.w};
            const v2f vlo{v.x, v.y}, vhi{v.z, v.w};
            #pragma unroll
            for (int i = 0; i < 4; ++i) {
                acc0[i] += a[i][2 * q]     * ulo;
                acc0[i] += a[i][2 * q + 1] * uhi;
                acc1[i] += a[i][2 * q]     * vlo;
                acc1[i] += a[i][2 * q + 1] * vhi;
            }
        }
        const float f = fbuf[sq][t];   // 2 distinct addrs -> broadcast
        float cn[4];
        #pragma unroll
        for (int i = 0; i < 4; ++i) {
            float p0 = acc0[i].x + acc0[i].y;
            float p1 = acc1[i].x + acc1[i].y;
            p0 = red16(p0);
            p1 = red16(p1);
            const float ps = sq ? p1 : p0;            // per-lane seq select
            cn[i] = fmaf((&bd4.x)[i], f, ps);
        }
        if (writer) {
            const float4 cv = make_float4(cn[0], cn[1], cn[2], cn[3]);
            *w = cv;   // masked ds_write_b128 (8 lanes/wave)
            *o = cv;   // masked global_store_dwordx4
        }
        __syncthreads();
    };

    for (int t = 0; t < LSTEPS; t += 2) {
        step(r00, r01, w1, op, t);      op += ostride;
        step(r10, r11, w0, op, t + 1);  op += ostride;
    }
}

extern "C" void kernel_launch(void* const* d_in, const int* in_sizes, int n_in,
                              void* d_out, int out_size, void* d_ws, size_t ws_size,
                              hipStream_t stream) {
    const float* inp = (const float*)d_in[0];   // (8,64,1024) fp32
    const float* A   = (const float*)d_in[1];   // (256,256)   fp32
    const float* B   = (const float*)d_in[2];   // (256,)      fp32
    float* out = (float*)d_out;                 // (1024,8,64,256) fp32
    hipLaunchKernelGGL(hippo_legt_kernel, dim3(256), dim3(1024), 0, stream,
                       inp, A, B, out);
}

// Round 3
// 1827.260 us; speedup vs baseline: 1.0186x; 1.0186x over previous
//
#include <hip/hip_runtime.h>

// HiPPO-LegT forward scan, fp32.
//   c_t = c_{t-1} @ A^T + f_t * B    (512 sequences, N=256, L=1024)
//
// R3. Evidence: R0/R1/R2 all land at ~3400-3900 cyc/step despite VALU halved
// (R1) and DS quartered (R2) => a fixed per-step cost dominates. Theory: the
// per-step global store + __syncthreads() => hipcc emits
// s_waitcnt vmcnt(0) lgkmcnt(0) before s_barrier, so every step drains the
// output store to memory-ack, fully exposed (1 WG/CU, nothing overlaps it).
// Fix: raw s_barrier + explicit lgkmcnt(0) only (HK/8-phase idiom). LDS
// producer->consumer ordering kept; global stores float across barriers
// (read only by host after kernel end; <=2 outstanding, vmcnt queue is 63).
// Prediction: dur 1650 -> ~700-1000us, VALUBusy -> 60-90%, conflicts same.
// Falsifier: dur >= 1200us => floor is additive latency, not the drain =>
// R4 = chunked-scan rewrite (A-power carry GEMMs via d_ws, no per-step barrier).

#define LSTEPS 1024
#define NCH 20   // LDS chunk stride in floats: 16 payload + 4 pad

typedef float v2f __attribute__((ext_vector_type(2)));

#define DPP_ADD(v, ctrl) \
  ((v) + __int_as_float(__builtin_amdgcn_update_dpp( \
       0, __float_as_int(v), (ctrl), 0xF, 0xF, false)))

__device__ __forceinline__ float red16(float v) {
  // all-reduce over the 16 lanes of a DPP row (lanes ck=0..15 of a rowtile)
  v = DPP_ADD(v, 0xB1);   // quad_perm [1,0,3,2]  : + lane^1
  v = DPP_ADD(v, 0x4E);   // quad_perm [2,3,0,1]  : + lane^2  -> quad sums
  v = DPP_ADD(v, 0x124);  // row_ror:4            : + next quad
  v = DPP_ADD(v, 0x128);  // row_ror:8            : + other half
  return v;
}

// Barrier without the vmcnt(0) drain: LDS ordering only.
__device__ __forceinline__ void lds_barrier() {
  __builtin_amdgcn_sched_barrier(0);
  asm volatile("s_waitcnt lgkmcnt(0)" ::: "memory");
  __builtin_amdgcn_s_barrier();
  __builtin_amdgcn_sched_barrier(0);
}

__global__ __launch_bounds__(1024, 4) void hippo_legt_kernel(
    const float* __restrict__ inp,   // (512, 1024) = (B*M, L)
    const float* __restrict__ A,     // (256, 256) row-major (discrete Ad)
    const float* __restrict__ Bvec,  // (256)      (discrete Bd)
    float* __restrict__ out)         // (1024, 512, 256)
{
    __shared__ __attribute__((aligned(16))) float cbuf[2][2][16][NCH]; // [buf][seq][chunk][pad]
    __shared__ __attribute__((aligned(16))) float fbuf[2][LSTEPS];

    const int tid  = threadIdx.x;
    const int rt   = tid >> 4;   // rowtile 0..63 : rows 4rt..4rt+3
    const int ck   = tid & 15;   // col-chunk 0..15: cols 16ck..16ck+15
    const int sq   = ck & 1;     // writer lanes: ck==0 -> seq0, ck==1 -> seq1
    const int seq0 = blockIdx.x * 2;

    // A fragment: A[4rt+i][16ck + 0..15] as v2f pairs -> 64 VGPRs.
    v2f a[4][8];
    #pragma unroll
    for (int i = 0; i < 4; ++i) {
        const float4* Ar =
            reinterpret_cast<const float4*>(A + (size_t)(4 * rt + i) * 256 + 16 * ck);
        #pragma unroll
        for (int q = 0; q < 4; ++q) {
            const float4 t = Ar[q];
            a[i][2 * q]     = v2f{t.x, t.y};
            a[i][2 * q + 1] = v2f{t.z, t.w};
        }
    }
    const float4 bd4 = reinterpret_cast<const float4*>(Bvec)[rt];

    // Preload f for both sequences: 2048 floats = 512 float4, coalesced.
    if (tid < 512) {
        reinterpret_cast<float4*>(&fbuf[0][0])[tid] =
            reinterpret_cast<const float4*>(inp + (size_t)seq0 * LSTEPS)[tid];
    }
    // Zero initial state buffer (buf 0, both seqs): 2*16*20 = 640 floats.
    if (tid < 2 * 16 * NCH) (&cbuf[0][0][0][0])[tid] = 0.0f;
    __syncthreads();   // once, outside the hot loop: full drain is fine here

    // Per-lane invariant addresses (no per-step address math).
    const float4* r00 = reinterpret_cast<const float4*>(&cbuf[0][0][ck][0]);
    const float4* r01 = reinterpret_cast<const float4*>(&cbuf[0][1][ck][0]);
    const float4* r10 = reinterpret_cast<const float4*>(&cbuf[1][0][ck][0]);
    const float4* r11 = reinterpret_cast<const float4*>(&cbuf[1][1][ck][0]);
    float4* w0 = reinterpret_cast<float4*>(&cbuf[0][sq][rt >> 2][(rt & 3) * 4]);
    float4* w1 = reinterpret_cast<float4*>(&cbuf[1][sq][rt >> 2][(rt & 3) * 4]);
    float4* op = reinterpret_cast<float4*>(out + (size_t)(seq0 + sq) * 256 + rt * 4);
    const bool writer = (ck < 2);
    const size_t ostride = (size_t)512 * 256 / 4;   // float4s per time step

    auto step = [&](const float4* __restrict__ r0, const float4* __restrict__ r1,
                    float4* w, float4* o, int t) {
        v2f acc0[4], acc1[4];
        // q = 0: initialize accumulators with pk_mul (no zero-init movs)
        {
            const float4 u = r0[0];
            const float4 v = r1[0];
            const v2f ulo{u.x, u.y}, uhi{u.z, u.w};
            const v2f vlo{v.x, v.y}, vhi{v.z, v.w};
            #pragma unroll
            for (int i = 0; i < 4; ++i) {
                acc0[i] = a[i][0] * ulo;  acc0[i] += a[i][1] * uhi;
                acc1[i] = a[i][0] * vlo;  acc1[i] += a[i][1] * vhi;
            }
        }
        #pragma unroll
        for (int q = 1; q < 4; ++q) {
            const float4 u = r0[q];
            const float4 v = r1[q];
            const v2f ulo{u.x, u.y}, uhi{u.z, u.w};
            const v2f vlo{v.x, v.y}, vhi{v.z, v.w};
            #pragma unroll
            for (int i = 0; i < 4; ++i) {
                acc0[i] += a[i][2 * q]     * ulo;
                acc0[i] += a[i][2 * q + 1] * uhi;
                acc1[i] += a[i][2 * q]     * vlo;
                acc1[i] += a[i][2 * q + 1] * vhi;
            }
        }
        const float f = fbuf[sq][t];   // 2 distinct addrs -> broadcast
        float cn[4];
        #pragma unroll
        for (int i = 0; i < 4; ++i) {
            float p0 = acc0[i].x + acc0[i].y;
            float p1 = acc1[i].x + acc1[i].y;
            p0 = red16(p0);
            p1 = red16(p1);
            const float ps = sq ? p1 : p0;            // per-lane seq select
            cn[i] = fmaf((&bd4.x)[i], f, ps);
        }
        if (writer) {
            const float4 cv = make_float4(cn[0], cn[1], cn[2], cn[3]);
            *w = cv;   // masked ds_write_b128 (8 lanes/wave)
            *o = cv;   // masked global_store_dwordx4 — floats across barriers
        }
        lds_barrier();   // lgkmcnt(0) + s_barrier, NO vmcnt drain
    };

    for (int t = 0; t < LSTEPS; t += 2) {
        step(r00, r01, w1, op, t);      op += ostride;
        step(r10, r11, w0, op, t + 1);  op += ostride;
    }
    // kernel-end implicit drain covers the in-flight global stores
}

extern "C" void kernel_launch(void* const* d_in, const int* in_sizes, int n_in,
                              void* d_out, int out_size, void* d_ws, size_t ws_size,
                              hipStream_t stream) {
    const float* inp = (const float*)d_in[0];   // (8,64,1024) fp32
    const float* A   = (const float*)d_in[1];   // (256,256)   fp32
    const float* B   = (const float*)d_in[2];   // (256,)      fp32
    float* out = (float*)d_out;                 // (1024,8,64,256) fp32
    hipLaunchKernelGGL(hippo_legt_kernel, dim3(256), dim3(1024), 0, stream,
                       inp, A, B, out);
}